// Round 5
// baseline (263.395 us; speedup 1.0000x reference)
//
#include <hip/hip_runtime.h>
#include <hip/hip_bf16.h>
#include <math.h>

// Problem constants
#define NB   4096      // graphs
#define MM   64        // points per graph
#define KNN  3
#define FX   59
#define H    128
#define NN   (NB*MM)       // 262144 nodes
#define NE   (NN*KNN)      // 786432 edges
#define C1   256
#define EPSB 1e-5f
#define NSH  16            // atomic shadow copies

typedef __attribute__((ext_vector_type(8))) short short8;   // 8 bf16 (4 VGPRs)
typedef __attribute__((ext_vector_type(4))) float f32x4;

__device__ __forceinline__ float wave_red(float v) {
#pragma unroll
    for (int m = 32; m >= 1; m >>= 1) v += __shfl_xor(v, m, 64);
    return v;
}

__device__ __forceinline__ void atomAddF(float* p, float v) {
    __hip_atomic_fetch_add(p, v, __ATOMIC_RELAXED, __HIP_MEMORY_SCOPE_AGENT);
}

// pack two f32 -> u32 of 2 bf16 (lo = a, hi = b), RNE (v_cvt_pk_bf16_f32)
__device__ __forceinline__ unsigned int pack_bf2(float a, float b) {
    union { __hip_bfloat162 h; unsigned int u; } cv;
    cv.h = __float22bfloat162_rn(make_float2(a, b));
    return cv.u;
}

// ---------------------------------------------------------------------------
// K1 (fused W1-prep + prepx + kNN + MFMA1 + combine), 512 threads / 8 waves.
// bf16 conversions via hw cvt_pk (same RNE as the old manual f2bf).
// ---------------------------------------------------------------------------
__global__ __launch_bounds__(512, 8) void k_knn_mfma1(
    const float* __restrict__ x, const float* __restrict__ pos,
    const float* __restrict__ W1, const float* __restrict__ b1,
    unsigned short* __restrict__ h1max,
    float* __restrict__ S1sh, float* __restrict__ Q1sh)
{
    __shared__ float pos_s[MM * 3];
    __shared__ int   nbr_s[MM * 3];
    __shared__ float b1_s[H];
    __shared__ float w1p_s[3 * H];
    __shared__ __align__(16) unsigned short a_s[MM * 72];    // 64x64 bf16, stride 72
    __shared__ __align__(16) unsigned int   u_s32[MM * 66];  // 64 x 66 u32

    const int blk = blockIdx.x, tid = threadIdx.x;
    const float* xg = x + (size_t)blk * MM * FX;
    const float* pg = pos + (size_t)blk * MM * 3;

    // --- fused prepx: thread = eighth of node row (8 cols), f32 -> bf16 -> a_s
    {
        const int node = tid >> 3, c0g = (tid & 7) * 8;
        float v[8];
#pragma unroll
        for (int i = 0; i < 8; ++i) {
            int cI = c0g + i;
            v[i] = (cI < FX) ? xg[node * FX + cI]
                             : ((cI < 62) ? pg[node * 3 + (cI - FX)] : 0.f);
        }
        uint4 pk;
        pk.x = pack_bf2(v[0], v[1]); pk.y = pack_bf2(v[2], v[3]);
        pk.z = pack_bf2(v[4], v[5]); pk.w = pack_bf2(v[6], v[7]);
        *(uint4*)(a_s + node * 72 + c0g) = pk;
    }
    if (tid < MM * 3) pos_s[tid] = pg[tid];
    if (tid < H) b1_s[tid] = b1[tid];
    if (tid < 3 * H) w1p_s[tid] = W1[(FX + (tid >> 7)) * H + (tid & 127)];

    // --- W1 fragment loads straight from global (L2-hot)
    const int lane = tid & 63;
    const int w    = tid >> 6;          // 8 waves
    const int m    = lane & 15;
    const int kg   = lane >> 4;
    const int ch   = w * 16 + m;        // wave owns channels [w*16, w*16+16)

    short8 bfr[2];
#pragma unroll
    for (int kc = 0; kc < 2; ++kc) {
        float t8[8];
#pragma unroll
        for (int i = 0; i < 8; ++i) {
            int k = kc * 32 + kg * 8 + i;
            t8[i] = (k < 62) ? W1[k * H + ch] : 0.f;
        }
        uint4 pk;
        pk.x = pack_bf2(t8[0], t8[1]); pk.y = pack_bf2(t8[2], t8[3]);
        pk.z = pack_bf2(t8[4], t8[5]); pk.w = pack_bf2(t8[6], t8[7]);
        bfr[kc] = *(short8*)&pk;
    }
    __syncthreads();

    // --- parallel kNN: 8 threads per node, each scans 8 candidates; merge
    //     via shfl_xor(1,2,4). Lexicographic (d, idx) == top_k tie-break.
    {
        const int node = tid >> 3, q = tid & 7;
        const float px = pos_s[node * 3 + 0];
        const float py = pos_s[node * 3 + 1];
        const float pz = pos_s[node * 3 + 2];
        float d0 = 1e30f, d1 = 1e30f, d2 = 1e30f;
        int   i0 = 1 << 30, i1 = 1 << 30, i2 = 1 << 30;
        for (int jj = 0; jj < 8; ++jj) {
            int j = q * 8 + jj;
            if (j == node) continue;
            float dx = pos_s[j * 3 + 0] - px;
            float dy = pos_s[j * 3 + 1] - py;
            float dz = pos_s[j * 3 + 2] - pz;
            float d = dx * dx + dy * dy + dz * dz;
            bool b2v = (d < d2) || (d == d2 && j < i2);
            bool b1v = (d < d1) || (d == d1 && j < i1);
            bool b0v = (d < d0) || (d == d0 && j < i0);
            float nd2 = b1v ? d1 : d; int ni2 = b1v ? i1 : j;
            float nd1 = b0v ? d0 : d; int ni1 = b0v ? i0 : j;
            d2 = b2v ? nd2 : d2; i2 = b2v ? ni2 : i2;
            d1 = b1v ? nd1 : d1; i1 = b1v ? ni1 : i1;
            d0 = b0v ? d   : d0; i0 = b0v ? j   : i0;
        }
#pragma unroll
        for (int mq = 1; mq <= 4; mq <<= 1) {
            float e[3]; int f[3];
            e[0] = __shfl_xor(d0, mq, 64); f[0] = __shfl_xor(i0, mq, 64);
            e[1] = __shfl_xor(d1, mq, 64); f[1] = __shfl_xor(i1, mq, 64);
            e[2] = __shfl_xor(d2, mq, 64); f[2] = __shfl_xor(i2, mq, 64);
#pragma unroll
            for (int t3 = 0; t3 < 3; ++t3) {
                float ev = e[t3]; int fv = f[t3];
                bool b2v = (ev < d2) || (ev == d2 && fv < i2);
                bool b1v = (ev < d1) || (ev == d1 && fv < i1);
                bool b0v = (ev < d0) || (ev == d0 && fv < i0);
                float nd2 = b1v ? d1 : ev; int ni2 = b1v ? i1 : fv;
                float nd1 = b0v ? d0 : ev; int ni1 = b0v ? i0 : fv;
                d2 = b2v ? nd2 : d2; i2 = b2v ? ni2 : i2;
                d1 = b1v ? nd1 : d1; i1 = b1v ? ni1 : i1;
                d0 = b0v ? ev  : d0; i0 = b0v ? fv  : i0;
            }
        }
        if (q == 0) {
            nbr_s[node * 3 + 0] = i0;
            nbr_s[node * 3 + 1] = i1;
            nbr_s[node * 3 + 2] = i2;
        }
    }

    // --- MFMA (swapped operands): D tile = [16 ch][16 node], wave w = 16 ch.
    f32x4 acc[4];
#pragma unroll
    for (int rt = 0; rt < 4; ++rt) acc[rt] = (f32x4){0.f, 0.f, 0.f, 0.f};

#pragma unroll
    for (int kc = 0; kc < 2; ++kc)
#pragma unroll
        for (int rt = 0; rt < 4; ++rt) {
            short8 a = *(const short8*)(a_s + (rt * 16 + m) * 72 + kc * 32 + kg * 8);
            acc[rt] = __builtin_amdgcn_mfma_f32_16x16x32_bf16(bfr[kc], a, acc[rt], 0, 0, 0);
        }
#pragma unroll
    for (int rt = 0; rt < 4; ++rt) {
        int node = rt * 16 + m;
        int pidx = 8 * w + 2 * kg;     // u32 index = (channel base)/2
        uint2 val;
        val.x = pack_bf2(acc[rt][0], acc[rt][1]);
        val.y = pack_bf2(acc[rt][2], acc[rt][3]);
        *(uint2*)(u_s32 + node * 66 + pidx) = val;
    }
    __syncthreads();

    // --- combine: wave w handles nodes [w*8, w*8+8); lane owns channel pair.
    const int c0 = 2 * lane, c1v = 2 * lane + 1;
    const float wpa0 = w1p_s[c0],      wpa1 = w1p_s[H + c0],  wpa2 = w1p_s[2 * H + c0];
    const float wpb0 = w1p_s[c1v],     wpb1 = w1p_s[H + c1v], wpb2 = w1p_s[2 * H + c1v];
    const float b1a = b1_s[c0], b1b = b1_s[c1v];
    float s0 = 0.f, s1 = 0.f, q0 = 0.f, q1 = 0.f;
    unsigned int* hout32 = (unsigned int*)(h1max + (size_t)blk * MM * H);
#pragma unroll
    for (int ii = 0; ii < 8; ++ii) {
        int node = w * 8 + ii;
        int j0 = nbr_s[node * 3 + 0];
        int j1 = nbr_s[node * 3 + 1];
        int j2 = nbr_s[node * 3 + 2];
        float px = pos_s[node * 3 + 0], py = pos_s[node * 3 + 1], pz = pos_s[node * 3 + 2];
        float basea = b1a - (px * wpa0 + py * wpa1 + pz * wpa2);
        float baseb = b1b - (px * wpb0 + py * wpb1 + pz * wpb2);
        unsigned int v0 = u_s32[j0 * 66 + lane];
        unsigned int v1 = u_s32[j1 * 66 + lane];
        unsigned int v2 = u_s32[j2 * 66 + lane];
        float h0a = fmaxf(__uint_as_float(v0 << 16) + basea, 0.f);
        float h1a = fmaxf(__uint_as_float(v1 << 16) + basea, 0.f);
        float h2a = fmaxf(__uint_as_float(v2 << 16) + basea, 0.f);
        float h0b = fmaxf(__uint_as_float(v0 & 0xffff0000u) + baseb, 0.f);
        float h1b = fmaxf(__uint_as_float(v1 & 0xffff0000u) + baseb, 0.f);
        float h2b = fmaxf(__uint_as_float(v2 & 0xffff0000u) + baseb, 0.f);
        s0 += h0a + h1a + h2a; q0 += h0a * h0a + h1a * h1a + h2a * h2a;
        s1 += h0b + h1b + h2b; q1 += h0b * h0b + h1b * h1b + h2b * h2b;
        float ma = fmaxf(fmaxf(h0a, h1a), h2a);
        float mb = fmaxf(fmaxf(h0b, h1b), h2b);
        hout32[node * 64 + lane] = pack_bf2(ma, mb);
    }
    __syncthreads();   // all combine reads of u_s32 done before overlay

    // --- in-block BN1 partial reduce, then shadowed atomic accumulate
    float* s_red = (float*)a_s;
    float* q_red = (float*)u_s32;
    *(float2*)(s_red + w * 128 + c0) = make_float2(s0, s1);
    *(float2*)(q_red + w * 128 + c0) = make_float2(q0, q1);
    __syncthreads();
    const int sel = blk & (NSH - 1);
    if (tid < 128) {
        float S = 0.f;
#pragma unroll
        for (int ww = 0; ww < 8; ++ww) S += s_red[ww * 128 + tid];
        atomAddF(&S1sh[sel * H + tid], S);
    } else if (tid < 256) {
        int t2 = tid - 128;
        float Q = 0.f;
#pragma unroll
        for (int ww = 0; ww < 8; ++ww) Q += q_red[ww * 128 + t2];
        atomAddF(&Q1sh[sel * H + t2], Q);
    }
}

// ---------------------------------------------------------------------------
// K3 (+prep2 fold): per block (512 thr, 2 graphs): fold BN1 shadows -> affine
// in LDS; build W2t fragments in-register from W2 (loads reused for the b2p
// butterfly sum); MFMA; graphsum + shadowed BN2 atomics. grid = 2048.
// ---------------------------------------------------------------------------
__global__ __launch_bounds__(512, 2) void k_mfma2(
    const unsigned short* __restrict__ h1max, const float* __restrict__ W2,
    const float* __restrict__ S1sh, const float* __restrict__ Q1sh,
    const float* __restrict__ g1, const float* __restrict__ be1,
    const float* __restrict__ b2,
    float* __restrict__ graphsum, float* __restrict__ S2sh, float* __restrict__ Q2sh)
{
    __shared__ __align__(16) unsigned short a_s[2 * MM * 136]; // 2x 64x128 bf16, stride 136
    __shared__ float af_s[H], cf_s[H];
    const int blk = blockIdx.x, tid = threadIdx.x;
    const unsigned short* hg = h1max + (size_t)blk * 2 * MM * H;

    // BN1 affine fold (threads 0-127)
    if (tid < H) {
        float S = 0.f, Q = 0.f;
#pragma unroll
        for (int i = 0; i < NSH; ++i) { S += S1sh[i * H + tid]; Q += Q1sh[i * H + tid]; }
        float mu  = S * (1.f / (float)NE);
        float var = Q * (1.f / (float)NE) - mu * mu;
        float a   = g1[tid] * rsqrtf(var + EPSB);
        af_s[tid] = a;
        cf_s[tid] = be1[tid] - mu * a;
    }
    // stage 2 graphs (contiguous rows 0..127)
    for (int t = tid; t < 128 * 16; t += 512) {
        int row = t >> 4, col8 = (t & 15) * 8;
        *(short8*)(a_s + row * 136 + col8) = *(const short8*)(hg + row * H + col8);
    }
    __syncthreads();

    const int lane = tid & 63, w = tid >> 6;
    const int wg = w >> 2, wcol = (w & 3) * 32;   // waves 0-3: graph0, 4-7: graph1
    const int m = lane & 15, kg = lane >> 4;

    // W2t fragments + b2p in-register (prep2 fold)
    short8 bfr[2][4];
    float bp[2];
#pragma unroll
    for (int ct = 0; ct < 2; ++ct) {
        const int n = wcol + ct * 16 + m;
        float bsum = 0.f;
#pragma unroll
        for (int kc = 0; kc < 4; ++kc) {
            float tt[8];
#pragma unroll
            for (int i = 0; i < 8; ++i) {
                int k = kc * 32 + kg * 8 + i;
                float wv = W2[k * H + n];
                tt[i] = af_s[k] * wv;
                bsum += cf_s[k] * wv;
            }
            uint4 pk;
            pk.x = pack_bf2(tt[0], tt[1]); pk.y = pack_bf2(tt[2], tt[3]);
            pk.z = pack_bf2(tt[4], tt[5]); pk.w = pack_bf2(tt[6], tt[7]);
            bfr[ct][kc] = *(short8*)&pk;
        }
        bsum += __shfl_xor(bsum, 16, 64);
        bsum += __shfl_xor(bsum, 32, 64);
        bp[ct] = b2[n] + bsum;
    }

    const unsigned short* ar = a_s + wg * MM * 136;
    f32x4 acc[4][2];
#pragma unroll
    for (int rt = 0; rt < 4; ++rt)
#pragma unroll
        for (int ct = 0; ct < 2; ++ct) acc[rt][ct] = (f32x4){0.f, 0.f, 0.f, 0.f};

#pragma unroll
    for (int kc = 0; kc < 4; ++kc)
#pragma unroll
        for (int rt = 0; rt < 4; ++rt) {
            short8 a = *(const short8*)(ar + (rt * 16 + m) * 136 + kc * 32 + kg * 8);
#pragma unroll
            for (int ct = 0; ct < 2; ++ct)
                acc[rt][ct] = __builtin_amdgcn_mfma_f32_16x16x32_bf16(a, bfr[ct][kc], acc[rt][ct], 0, 0, 0);
        }

    const int gidx = blk * 2 + wg;
    const int sel  = gidx & (NSH - 1);
#pragma unroll
    for (int ct = 0; ct < 2; ++ct) {
        float bv = bp[ct];
        float s = 0.f, q = 0.f;
#pragma unroll
        for (int rt = 0; rt < 4; ++rt)
#pragma unroll
            for (int r = 0; r < 4; ++r) {
                float v = fmaxf(acc[rt][ct][r] + bv, 0.f);
                s += v; q += v * v;
            }
        s += __shfl_xor(s, 16, 64); q += __shfl_xor(q, 16, 64);
        s += __shfl_xor(s, 32, 64); q += __shfl_xor(q, 32, 64);
        if (lane < 16) {
            int col = wcol + ct * 16 + lane;
            graphsum[(size_t)gidx * H + col] = s;
            atomAddF(&S2sh[sel * H + col], s);
            atomAddF(&Q2sh[sel * H + col], q);
        }
    }
}

// ---------------------------------------------------------------------------
// k_tail2 (cls1 + cls2 + final in one kernel; 256 blocks x 256 thr, all
// co-resident). Cross-block data ONLY via device-scope atomics; two atomic
// spin barriers (no L2 flushes — unlike coop grid.sync). c1 stays in LDS.
// ---------------------------------------------------------------------------
__global__ __launch_bounds__(256) void k_tail2(
    const float* __restrict__ graphsum,
    const float* __restrict__ S2sh, const float* __restrict__ Q2sh,
    const float* __restrict__ g2, const float* __restrict__ be2,
    const float* __restrict__ Wc1, const float* __restrict__ bc1,
    const float* __restrict__ gc1, const float* __restrict__ bec1,
    const float* __restrict__ Wc2, const float* __restrict__ bc2,
    const float* __restrict__ gc2, const float* __restrict__ bec2,
    float* __restrict__ S3, float* __restrict__ Q3,
    float* __restrict__ SzQz, int* __restrict__ cnts,
    float* __restrict__ out)
{
    __shared__ float a2_s[H], c2_s[H];
    __shared__ float pooled_s[16 * H];
    __shared__ float c1_s[16][C1 + 4];
    __shared__ float a3_s[C1], c3_s[C1], w3_s[C1];
    __shared__ float zloc[16];
    const int blk = blockIdx.x, tid = threadIdx.x;
    const int g0 = blk * 16;

    // affine2 from shadows (plain loads; produced by previous kernel)
    if (tid < H) {
        float S = 0.f, Q = 0.f;
#pragma unroll
        for (int i = 0; i < NSH; ++i) { S += S2sh[i * H + tid]; Q += Q2sh[i * H + tid]; }
        float mu  = S * (1.f / (float)NN);
        float var = Q * (1.f / (float)NN) - mu * mu;
        float a   = g2[tid] * rsqrtf(var + EPSB);
        a2_s[tid] = a;
        c2_s[tid] = be2[tid] - mu * a;
    }
    __syncthreads();
    for (int t = tid; t < 16 * H; t += 256) {
        int f = t & 127;
        pooled_s[t] = a2_s[f] * (graphsum[(size_t)g0 * H + t] * (1.f / 64.f)) + c2_s[f];
    }
    __syncthreads();

    // cls1: c = tid; 16 graphs; c1 stays in LDS
    {
        const int c = tid;
        float acc[16];
        const float bias = bc1[c];
#pragma unroll
        for (int gi = 0; gi < 16; ++gi) acc[gi] = bias;
        for (int f = 0; f < H; ++f) {
            float wv = Wc1[f * C1 + c];
#pragma unroll
            for (int gi = 0; gi < 16; ++gi) acc[gi] += pooled_s[gi * H + f] * wv;
        }
        float s = 0.f, q = 0.f;
#pragma unroll
        for (int gi = 0; gi < 16; ++gi) {
            float h = fmaxf(acc[gi], 0.f);
            c1_s[gi][c] = h;
            s += h; q += h * h;
        }
        atomAddF(&S3[c], s);
        atomAddF(&Q3[c], q);
    }
    __syncthreads();   // all 256 threads' atomics drained (vmcnt) before count
    if (tid == 0) {
        __hip_atomic_fetch_add(&cnts[0], 1, __ATOMIC_ACQ_REL, __HIP_MEMORY_SCOPE_AGENT);
        while (__hip_atomic_load(&cnts[0], __ATOMIC_ACQUIRE, __HIP_MEMORY_SCOPE_AGENT) < 256) {}
    }
    __syncthreads();

    // affine3 (atomic loads -> coherent path)
    {
        float S = __hip_atomic_load(&S3[tid], __ATOMIC_RELAXED, __HIP_MEMORY_SCOPE_AGENT);
        float Q = __hip_atomic_load(&Q3[tid], __ATOMIC_RELAXED, __HIP_MEMORY_SCOPE_AGENT);
        float mu  = S * (1.f / (float)NB);
        float var = Q * (1.f / (float)NB) - mu * mu;
        float a   = gc1[tid] * rsqrtf(var + EPSB);
        a3_s[tid] = a;
        c3_s[tid] = bec1[tid] - mu * a;
        w3_s[tid] = Wc2[tid];
    }
    __syncthreads();

    // cls2 from LDS c1 (16 lanes per graph)
    {
        const int gi = tid >> 4, part = tid & 15;
        float acc3 = 0.f;
#pragma unroll
        for (int i = 0; i < 16; i += 4) {
            int f = part * 16 + i;
            float4 cv = *(const float4*)&c1_s[gi][f];
            acc3 += (a3_s[f + 0] * cv.x + c3_s[f + 0]) * w3_s[f + 0];
            acc3 += (a3_s[f + 1] * cv.y + c3_s[f + 1]) * w3_s[f + 1];
            acc3 += (a3_s[f + 2] * cv.z + c3_s[f + 2]) * w3_s[f + 2];
            acc3 += (a3_s[f + 3] * cv.w + c3_s[f + 3]) * w3_s[f + 3];
        }
#pragma unroll
        for (int mm = 1; mm <= 8; mm <<= 1) acc3 += __shfl_xor(acc3, mm, 64);
        if (part == 0) zloc[gi] = fmaxf(acc3 + bc2[0], 0.f);
    }
    __syncthreads();
    if (tid == 0) {
        float s = 0.f, q = 0.f;
#pragma unroll
        for (int i = 0; i < 16; ++i) { float zz = zloc[i]; s += zz; q += zz * zz; }
        atomAddF(&SzQz[0], s);
        atomAddF(&SzQz[1], q);
        __hip_atomic_fetch_add(&cnts[1], 1, __ATOMIC_ACQ_REL, __HIP_MEMORY_SCOPE_AGENT);
        while (__hip_atomic_load(&cnts[1], __ATOMIC_ACQUIRE, __HIP_MEMORY_SCOPE_AGENT) < 256) {}
    }
    __syncthreads();

    if (tid < 16) {
        float S = __hip_atomic_load(&SzQz[0], __ATOMIC_RELAXED, __HIP_MEMORY_SCOPE_AGENT);
        float Q = __hip_atomic_load(&SzQz[1], __ATOMIC_RELAXED, __HIP_MEMORY_SCOPE_AGENT);
        float mu  = S * (1.f / 4096.f);
        float var = Q * (1.f / 4096.f) - mu * mu;
        float a   = gc2[0] * rsqrtf(var + EPSB);
        float cb  = bec2[0] - mu * a;
        float v = a * zloc[tid] + cb;
        out[g0 + tid] = 1.f / (1.f + expf(-v));
    }
}

extern "C" void kernel_launch(void* const* d_in, const int* in_sizes, int n_in,
                              void* d_out, int out_size, void* d_ws, size_t ws_size,
                              hipStream_t stream)
{
    const float* x    = (const float*)d_in[0];
    const float* pos  = (const float*)d_in[1];
    // d_in[2] = batch (int32) — graphs are contiguous 64-node chunks; unused
    const float* W1   = (const float*)d_in[3];
    const float* b1   = (const float*)d_in[4];
    const float* g1   = (const float*)d_in[5];
    const float* be1  = (const float*)d_in[6];
    const float* W2   = (const float*)d_in[7];
    const float* b2   = (const float*)d_in[8];
    const float* g2   = (const float*)d_in[9];
    const float* be2  = (const float*)d_in[10];
    const float* Wc1  = (const float*)d_in[11];
    const float* bc1  = (const float*)d_in[12];
    const float* gc1  = (const float*)d_in[13];
    const float* bec1 = (const float*)d_in[14];
    const float* Wc2  = (const float*)d_in[15];
    const float* bc2  = (const float*)d_in[16];
    const float* gc2  = (const float*)d_in[17];
    const float* bec2 = (const float*)d_in[18];
    float* out = (float*)d_out;

    float* ws = (float*)d_ws;
    size_t off = 0;
    auto alloc = [&](size_t n) { float* p = ws + off; off += n; return p; };
    unsigned short* h1max = (unsigned short*)alloc((size_t)NN * H / 2);  // bf16, 67 MB
    float* graphsum = alloc((size_t)NB * H);
    // atomic accumulators (contiguous; zeroed by one memset per iteration)
    const size_t ATOMN = (size_t)4 * NSH * H + 2 * C1 + 2 + 2;
    float* atomics = alloc(ATOMN);
    float* S1sh = atomics;
    float* Q1sh = S1sh + NSH * H;
    float* S2sh = Q1sh + NSH * H;
    float* Q2sh = S2sh + NSH * H;
    float* S3   = Q2sh + NSH * H;
    float* Q3   = S3 + C1;
    float* SzQz = Q3 + C1;
    int*   cnts = (int*)(SzQz + 2);

    hipMemsetAsync(atomics, 0, ATOMN * sizeof(float), stream);
    k_knn_mfma1<<<dim3(NB), dim3(512), 0, stream>>>(x, pos, W1, b1, h1max, S1sh, Q1sh);
    k_mfma2<<<dim3(NB / 2), dim3(512), 0, stream>>>(h1max, W2, S1sh, Q1sh, g1, be1, b2,
                                                    graphsum, S2sh, Q2sh);
    k_tail2<<<dim3(256), dim3(256), 0, stream>>>(graphsum, S2sh, Q2sh, g2, be2,
                                                 Wc1, bc1, gc1, bec1, Wc2, bc2, gc2, bec2,
                                                 S3, Q3, SzQz, cnts, out);
}

// Round 6
// 254.395 us; speedup vs baseline: 1.0354x; 1.0354x over previous
//
#include <hip/hip_runtime.h>
#include <hip/hip_bf16.h>
#include <math.h>

// Problem constants
#define NB   4096      // graphs
#define MM   64        // points per graph
#define KNN  3
#define FX   59
#define H    128
#define NN   (NB*MM)       // 262144 nodes
#define NE   (NN*KNN)      // 786432 edges
#define C1   256
#define EPSB 1e-5f
#define NSH  16            // atomic shadow copies (contention = NB/NSH per addr)

typedef __attribute__((ext_vector_type(8))) short short8;   // 8 bf16 (4 VGPRs)
typedef __attribute__((ext_vector_type(4))) float f32x4;

__device__ __forceinline__ float wave_red(float v) {
#pragma unroll
    for (int m = 32; m >= 1; m >>= 1) v += __shfl_xor(v, m, 64);
    return v;
}

__device__ __forceinline__ void atomAddF(float* p, float v) {
    __hip_atomic_fetch_add(p, v, __ATOMIC_RELAXED, __HIP_MEMORY_SCOPE_AGENT);
}

__device__ __forceinline__ unsigned short f2bf(float f) {
    union { float f; unsigned u; } v; v.f = f;
    unsigned r = v.u + 0x7fffu + ((v.u >> 16) & 1u);   // round-to-nearest-even
    return (unsigned short)(r >> 16);
}

// pack two f32 -> u32 of 2 bf16 (lo = a, hi = b), RNE (v_cvt_pk_bf16_f32)
__device__ __forceinline__ unsigned int pack_bf2(float a, float b) {
    union { __hip_bfloat162 h; unsigned int u; } cv;
    cv.h = __float22bfloat162_rn(make_float2(a, b));
    return cv.u;
}

// ---------------------------------------------------------------------------
// K1 (fused W1-prep + prepx + kNN + MFMA1 + combine), 512 threads / 8 waves.
// a_s uses a 16-B granule rotation ((g + row) & 7) to kill the 8-way bank
// conflict of the stride-144B layout (start bank was 4*(m+kg)%32 -> 8 groups;
// rotated banks are (2*row+g)%8 on reads and (2*node+g)%8 on writes — even).
// ---------------------------------------------------------------------------
__global__ __launch_bounds__(512, 8) void k_knn_mfma1(
    const float* __restrict__ x, const float* __restrict__ pos,
    const float* __restrict__ W1, const float* __restrict__ b1,
    unsigned short* __restrict__ h1max,
    float* __restrict__ S1sh, float* __restrict__ Q1sh)
{
    __shared__ float pos_s[MM * 3];
    __shared__ int   nbr_s[MM * 3];
    __shared__ float b1_s[H];
    __shared__ float w1p_s[3 * H];
    __shared__ __align__(16) unsigned short a_s[MM * 72];    // 64x64 bf16, stride 72, swizzled
    __shared__ __align__(16) unsigned int   u_s32[MM * 66];  // 64 x 66 u32

    const int blk = blockIdx.x, tid = threadIdx.x;
    const float* xg = x + (size_t)blk * MM * FX;
    const float* pg = pos + (size_t)blk * MM * 3;

    // --- fused prepx: thread = one 16B granule of a node row; swizzled store
    {
        const int node = tid >> 3, g = tid & 7;
        const int c0g = g * 8;
        float v[8];
#pragma unroll
        for (int i = 0; i < 8; ++i) {
            int cI = c0g + i;
            v[i] = (cI < FX) ? xg[node * FX + cI]
                             : ((cI < 62) ? pg[node * 3 + (cI - FX)] : 0.f);
        }
        uint4 pk;
        pk.x = pack_bf2(v[0], v[1]); pk.y = pack_bf2(v[2], v[3]);
        pk.z = pack_bf2(v[4], v[5]); pk.w = pack_bf2(v[6], v[7]);
        const int gs = (g + node) & 7;                    // granule rotation
        *(uint4*)(a_s + node * 72 + gs * 8) = pk;
    }
    if (tid < MM * 3) pos_s[tid] = pg[tid];
    if (tid < H) b1_s[tid] = b1[tid];
    if (tid < 3 * H) w1p_s[tid] = W1[(FX + (tid >> 7)) * H + (tid & 127)];

    // --- W1 fragment loads straight from global (L2-hot)
    const int lane = tid & 63;
    const int w    = tid >> 6;          // 8 waves
    const int m    = lane & 15;
    const int kg   = lane >> 4;
    const int ch   = w * 16 + m;        // wave owns channels [w*16, w*16+16)

    short8 bfr[2];
#pragma unroll
    for (int kc = 0; kc < 2; ++kc) {
        float t8[8];
#pragma unroll
        for (int i = 0; i < 8; ++i) {
            int k = kc * 32 + kg * 8 + i;
            t8[i] = (k < 62) ? W1[k * H + ch] : 0.f;
        }
        uint4 pk;
        pk.x = pack_bf2(t8[0], t8[1]); pk.y = pack_bf2(t8[2], t8[3]);
        pk.z = pack_bf2(t8[4], t8[5]); pk.w = pack_bf2(t8[6], t8[7]);
        bfr[kc] = *(short8*)&pk;
    }
    __syncthreads();

    // --- parallel kNN: 8 threads per node, each scans 8 candidates; merge
    //     via shfl_xor(1,2,4). Lexicographic (d, idx) == top_k tie-break.
    {
        const int node = tid >> 3, q = tid & 7;
        const float px = pos_s[node * 3 + 0];
        const float py = pos_s[node * 3 + 1];
        const float pz = pos_s[node * 3 + 2];
        float d0 = 1e30f, d1 = 1e30f, d2 = 1e30f;
        int   i0 = 1 << 30, i1 = 1 << 30, i2 = 1 << 30;
        for (int jj = 0; jj < 8; ++jj) {
            int j = q * 8 + jj;
            if (j == node) continue;
            float dx = pos_s[j * 3 + 0] - px;
            float dy = pos_s[j * 3 + 1] - py;
            float dz = pos_s[j * 3 + 2] - pz;
            float d = dx * dx + dy * dy + dz * dz;
            bool b2v = (d < d2) || (d == d2 && j < i2);
            bool b1v = (d < d1) || (d == d1 && j < i1);
            bool b0v = (d < d0) || (d == d0 && j < i0);
            float nd2 = b1v ? d1 : d; int ni2 = b1v ? i1 : j;
            float nd1 = b0v ? d0 : d; int ni1 = b0v ? i0 : j;
            d2 = b2v ? nd2 : d2; i2 = b2v ? ni2 : i2;
            d1 = b1v ? nd1 : d1; i1 = b1v ? ni1 : i1;
            d0 = b0v ? d   : d0; i0 = b0v ? j   : i0;
        }
#pragma unroll
        for (int mq = 1; mq <= 4; mq <<= 1) {
            float e[3]; int f[3];
            e[0] = __shfl_xor(d0, mq, 64); f[0] = __shfl_xor(i0, mq, 64);
            e[1] = __shfl_xor(d1, mq, 64); f[1] = __shfl_xor(i1, mq, 64);
            e[2] = __shfl_xor(d2, mq, 64); f[2] = __shfl_xor(i2, mq, 64);
#pragma unroll
            for (int t3 = 0; t3 < 3; ++t3) {
                float ev = e[t3]; int fv = f[t3];
                bool b2v = (ev < d2) || (ev == d2 && fv < i2);
                bool b1v = (ev < d1) || (ev == d1 && fv < i1);
                bool b0v = (ev < d0) || (ev == d0 && fv < i0);
                float nd2 = b1v ? d1 : ev; int ni2 = b1v ? i1 : fv;
                float nd1 = b0v ? d0 : ev; int ni1 = b0v ? i0 : fv;
                d2 = b2v ? nd2 : d2; i2 = b2v ? ni2 : i2;
                d1 = b1v ? nd1 : d1; i1 = b1v ? ni1 : i1;
                d0 = b0v ? ev  : d0; i0 = b0v ? fv  : i0;
            }
        }
        if (q == 0) {
            nbr_s[node * 3 + 0] = i0;
            nbr_s[node * 3 + 1] = i1;
            nbr_s[node * 3 + 2] = i2;
        }
    }

    // --- MFMA (swapped operands): D tile = [16 ch][16 node], wave w = 16 ch.
    f32x4 acc[4];
#pragma unroll
    for (int rt = 0; rt < 4; ++rt) acc[rt] = (f32x4){0.f, 0.f, 0.f, 0.f};

#pragma unroll
    for (int kc = 0; kc < 2; ++kc)
#pragma unroll
        for (int rt = 0; rt < 4; ++rt) {
            const int row = rt * 16 + m;
            const int gs = ((kc * 4 + kg) + row) & 7;      // granule rotation
            short8 a = *(const short8*)(a_s + row * 72 + gs * 8);
            acc[rt] = __builtin_amdgcn_mfma_f32_16x16x32_bf16(bfr[kc], a, acc[rt], 0, 0, 0);
        }
#pragma unroll
    for (int rt = 0; rt < 4; ++rt) {
        int node = rt * 16 + m;
        int pidx = 8 * w + 2 * kg;     // u32 index = (channel base)/2
        uint2 val;
        val.x = pack_bf2(acc[rt][0], acc[rt][1]);
        val.y = pack_bf2(acc[rt][2], acc[rt][3]);
        *(uint2*)(u_s32 + node * 66 + pidx) = val;
    }
    __syncthreads();

    // --- combine: wave w handles nodes [w*8, w*8+8); lane owns channel pair.
    const int c0 = 2 * lane, c1v = 2 * lane + 1;
    const float wpa0 = w1p_s[c0],      wpa1 = w1p_s[H + c0],  wpa2 = w1p_s[2 * H + c0];
    const float wpb0 = w1p_s[c1v],     wpb1 = w1p_s[H + c1v], wpb2 = w1p_s[2 * H + c1v];
    const float b1a = b1_s[c0], b1b = b1_s[c1v];
    float s0 = 0.f, s1 = 0.f, q0 = 0.f, q1 = 0.f;
    unsigned int* hout32 = (unsigned int*)(h1max + (size_t)blk * MM * H);
#pragma unroll
    for (int ii = 0; ii < 8; ++ii) {
        int node = w * 8 + ii;
        int j0 = nbr_s[node * 3 + 0];
        int j1 = nbr_s[node * 3 + 1];
        int j2 = nbr_s[node * 3 + 2];
        float px = pos_s[node * 3 + 0], py = pos_s[node * 3 + 1], pz = pos_s[node * 3 + 2];
        float basea = b1a - (px * wpa0 + py * wpa1 + pz * wpa2);
        float baseb = b1b - (px * wpb0 + py * wpb1 + pz * wpb2);
        unsigned int v0 = u_s32[j0 * 66 + lane];
        unsigned int v1 = u_s32[j1 * 66 + lane];
        unsigned int v2 = u_s32[j2 * 66 + lane];
        float h0a = fmaxf(__uint_as_float(v0 << 16) + basea, 0.f);
        float h1a = fmaxf(__uint_as_float(v1 << 16) + basea, 0.f);
        float h2a = fmaxf(__uint_as_float(v2 << 16) + basea, 0.f);
        float h0b = fmaxf(__uint_as_float(v0 & 0xffff0000u) + baseb, 0.f);
        float h1b = fmaxf(__uint_as_float(v1 & 0xffff0000u) + baseb, 0.f);
        float h2b = fmaxf(__uint_as_float(v2 & 0xffff0000u) + baseb, 0.f);
        s0 += h0a + h1a + h2a; q0 += h0a * h0a + h1a * h1a + h2a * h2a;
        s1 += h0b + h1b + h2b; q1 += h0b * h0b + h1b * h1b + h2b * h2b;
        float ma = fmaxf(fmaxf(h0a, h1a), h2a);
        float mb = fmaxf(fmaxf(h0b, h1b), h2b);
        hout32[node * 64 + lane] = pack_bf2(ma, mb);
    }
    __syncthreads();   // all combine reads of u_s32 done before overlay

    // --- in-block BN1 partial reduce, then shadowed atomic accumulate
    float* s_red = (float*)a_s;
    float* q_red = (float*)u_s32;
    *(float2*)(s_red + w * 128 + c0) = make_float2(s0, s1);
    *(float2*)(q_red + w * 128 + c0) = make_float2(q0, q1);
    __syncthreads();
    const int sel = blk & (NSH - 1);
    if (tid < 128) {
        float S = 0.f;
#pragma unroll
        for (int ww = 0; ww < 8; ++ww) S += s_red[ww * 128 + tid];
        atomAddF(&S1sh[sel * H + tid], S);
    } else if (tid < 256) {
        int t2 = tid - 128;
        float Q = 0.f;
#pragma unroll
        for (int ww = 0; ww < 8; ++ww) Q += q_red[ww * 128 + t2];
        atomAddF(&Q1sh[sel * H + t2], Q);
    }
}

// ---------------------------------------------------------------------------
// prep2: fold 16 BN1 shadows -> affine1 in-register; emit W2t (affine folded)
// and b2p. grid=128, blk=128.
// ---------------------------------------------------------------------------
__global__ __launch_bounds__(128) void k_prep2(
    const float* __restrict__ W2, const float* __restrict__ S1sh,
    const float* __restrict__ Q1sh, const float* __restrict__ g1,
    const float* __restrict__ be1, const float* __restrict__ b2,
    unsigned short* __restrict__ W2t, float* __restrict__ b2p)
{
    const int n = blockIdx.x, k = threadIdx.x;
    float S = 0.f, Q = 0.f;
#pragma unroll
    for (int i = 0; i < NSH; ++i) { S += S1sh[i * H + k]; Q += Q1sh[i * H + k]; }
    float mu  = S * (1.f / (float)NE);
    float var = Q * (1.f / (float)NE) - mu * mu;
    float a   = g1[k] * rsqrtf(var + EPSB);
    float cc  = be1[k] - mu * a;
    float wv  = W2[k * H + n];
    W2t[n * H + k] = f2bf(a * wv);
    float contrib = wave_red(cc * wv);
    __shared__ float red2[2];
    if ((k & 63) == 0) red2[k >> 6] = contrib;
    __syncthreads();
    if (k == 0) b2p[n] = b2[n] + red2[0] + red2[1];
}

// ---------------------------------------------------------------------------
// K3: h2 = relu(h1max(bf16) @ W2t + b2p) via MFMA; graphsum + shadowed
// atomic BN2 stats. LDS-staged (round-1 form). grid=4096, 256 thr.
// ---------------------------------------------------------------------------
__global__ __launch_bounds__(256) void k_mfma2(
    const unsigned short* __restrict__ h1max, const unsigned short* __restrict__ W2t,
    const float* __restrict__ b2p,
    float* __restrict__ graphsum, float* __restrict__ S2sh, float* __restrict__ Q2sh)
{
    __shared__ __align__(16) unsigned short a_s[MM * 136];  // 64x128 bf16, stride 136
    const int blk = blockIdx.x, tid = threadIdx.x;
    const unsigned short* hg = h1max + (size_t)blk * MM * H;
    for (int t = tid; t < MM * H / 8; t += 256) {
        int row = t >> 4, col8 = (t & 15) * 8;
        *(short8*)(a_s + row * 136 + col8) = *(const short8*)(hg + row * H + col8);
    }
    __syncthreads();

    const int lane = tid & 63, w = tid >> 6, wcol = w * 32;
    const int m = lane & 15, kg = lane >> 4;

    short8 bfr[2][4];
#pragma unroll
    for (int ct = 0; ct < 2; ++ct)
#pragma unroll
        for (int kc = 0; kc < 4; ++kc)
            bfr[ct][kc] = *(const short8*)(W2t + (wcol + ct * 16 + m) * H + kc * 32 + kg * 8);

    f32x4 acc[4][2];
#pragma unroll
    for (int rt = 0; rt < 4; ++rt)
#pragma unroll
        for (int ct = 0; ct < 2; ++ct) acc[rt][ct] = (f32x4){0.f, 0.f, 0.f, 0.f};

#pragma unroll
    for (int kc = 0; kc < 4; ++kc)
#pragma unroll
        for (int rt = 0; rt < 4; ++rt) {
            short8 a = *(const short8*)(a_s + (rt * 16 + m) * 136 + kc * 32 + kg * 8);
#pragma unroll
            for (int ct = 0; ct < 2; ++ct)
                acc[rt][ct] = __builtin_amdgcn_mfma_f32_16x16x32_bf16(a, bfr[ct][kc], acc[rt][ct], 0, 0, 0);
        }

    const int sel = blk & (NSH - 1);
#pragma unroll
    for (int ct = 0; ct < 2; ++ct) {
        float bv = b2p[wcol + ct * 16 + m];
        float s = 0.f, q = 0.f;
#pragma unroll
        for (int rt = 0; rt < 4; ++rt)
#pragma unroll
            for (int r = 0; r < 4; ++r) {
                float v = fmaxf(acc[rt][ct][r] + bv, 0.f);
                s += v; q += v * v;
            }
        s += __shfl_xor(s, 16, 64); q += __shfl_xor(q, 16, 64);
        s += __shfl_xor(s, 32, 64); q += __shfl_xor(q, 32, 64);
        if (lane < 16) {
            int col = wcol + ct * 16 + lane;
            graphsum[(size_t)blk * H + col] = s;
            atomAddF(&S2sh[sel * H + col], s);
            atomAddF(&Q2sh[sel * H + col], q);
        }
    }
}

// ---------------------------------------------------------------------------
// cls1: affine2 inline from shadows; pooled = BN2(graphsum/64);
// c1 = ReLU(pooled @ Wc1 + bc1); BN3 stats via direct atomics.
// grid=256, blk=256 (16 graphs per block).
// ---------------------------------------------------------------------------
__global__ __launch_bounds__(256) void k_cls1(
    const float* __restrict__ graphsum,
    const float* __restrict__ S2sh, const float* __restrict__ Q2sh,
    const float* __restrict__ g2, const float* __restrict__ be2,
    const float* __restrict__ Wc1, const float* __restrict__ bc1,
    float* __restrict__ c1raw, float* __restrict__ S3, float* __restrict__ Q3)
{
    __shared__ float a2_s[H], c2_s[H];
    const int blk = blockIdx.x, tid = threadIdx.x;
    if (tid < H) {
        float S = 0.f, Q = 0.f;
#pragma unroll
        for (int i = 0; i < NSH; ++i) { S += S2sh[i * H + tid]; Q += Q2sh[i * H + tid]; }
        float mu  = S * (1.f / (float)NN);
        float var = Q * (1.f / (float)NN) - mu * mu;
        float a   = g2[tid] * rsqrtf(var + EPSB);
        a2_s[tid] = a;
        c2_s[tid] = be2[tid] - mu * a;
    }
    __syncthreads();
    __shared__ float pooled_s[16 * H];
    const int g0 = blk * 16;
    for (int t = tid; t < 16 * H; t += 256) {
        int f = t & 127;
        pooled_s[t] = a2_s[f] * (graphsum[(size_t)g0 * H + t] * (1.f / 64.f)) + c2_s[f];
    }
    __syncthreads();
    const int c = tid;
    float acc[16];
    const float bias = bc1[c];
#pragma unroll
    for (int gi = 0; gi < 16; ++gi) acc[gi] = bias;
    for (int f = 0; f < H; ++f) {
        float wv = Wc1[f * C1 + c];
#pragma unroll
        for (int gi = 0; gi < 16; ++gi) acc[gi] += pooled_s[gi * H + f] * wv;
    }
    float s = 0.f, q = 0.f;
#pragma unroll
    for (int gi = 0; gi < 16; ++gi) {
        float h = fmaxf(acc[gi], 0.f);
        c1raw[(size_t)(g0 + gi) * C1 + c] = h;
        s += h; q += h * h;
    }
    atomAddF(&S3[c], s);
    atomAddF(&Q3[c], q);
}

// ---------------------------------------------------------------------------
// cls2: affine3 inline from S3/Q3; z = ReLU(BN3(c1) @ Wc2 + bc2);
// final-BN scalar stats via atomics. grid=256, blk=256 (16 lanes/graph).
// ---------------------------------------------------------------------------
__global__ __launch_bounds__(256) void k_cls2(
    const float* __restrict__ c1raw,
    const float* __restrict__ S3, const float* __restrict__ Q3,
    const float* __restrict__ gc1, const float* __restrict__ bec1,
    const float* __restrict__ Wc2, const float* __restrict__ bc2,
    float* __restrict__ z, float* __restrict__ SzQz)
{
    __shared__ float a3_s[C1], c3_s[C1], w3_s[C1];
    __shared__ float zloc[16];
    const int blk = blockIdx.x, tid = threadIdx.x;
    {
        float S = S3[tid], Q = Q3[tid];
        float mu  = S * (1.f / (float)NB);
        float var = Q * (1.f / (float)NB) - mu * mu;
        float a   = gc1[tid] * rsqrtf(var + EPSB);
        a3_s[tid] = a;
        c3_s[tid] = bec1[tid] - mu * a;
        w3_s[tid] = Wc2[tid];
    }
    __syncthreads();
    const int g0 = blk * 16;
    {
        const int gi = tid >> 4, part = tid & 15;
        const float* crow = c1raw + (size_t)(g0 + gi) * C1 + part * 16;
        float acc3 = 0.f;
#pragma unroll
        for (int i = 0; i < 16; i += 4) {
            float4 cv = *(const float4*)(crow + i);
            int f = part * 16 + i;
            acc3 += (a3_s[f + 0] * cv.x + c3_s[f + 0]) * w3_s[f + 0];
            acc3 += (a3_s[f + 1] * cv.y + c3_s[f + 1]) * w3_s[f + 1];
            acc3 += (a3_s[f + 2] * cv.z + c3_s[f + 2]) * w3_s[f + 2];
            acc3 += (a3_s[f + 3] * cv.w + c3_s[f + 3]) * w3_s[f + 3];
        }
#pragma unroll
        for (int mm = 1; mm <= 8; mm <<= 1) acc3 += __shfl_xor(acc3, mm, 64);
        if (part == 0) zloc[gi] = fmaxf(acc3 + bc2[0], 0.f);
    }
    __syncthreads();
    if (tid < 16) z[g0 + tid] = zloc[tid];
    if (tid == 0) {
        float s = 0.f, q = 0.f;
#pragma unroll
        for (int i = 0; i < 16; ++i) { float zz = zloc[i]; s += zz; q += zz * zz; }
        atomAddF(&SzQz[0], s);
        atomAddF(&SzQz[1], q);
    }
}

// ---------------------------------------------------------------------------
// final: BN over 4096 z (stats from SzQz) + sigmoid. grid=16, blk=256.
// ---------------------------------------------------------------------------
__global__ __launch_bounds__(256) void k_final(
    const float* __restrict__ z, const float* __restrict__ SzQz,
    const float* __restrict__ gc2, const float* __restrict__ bec2,
    float* __restrict__ out)
{
    const int g = blockIdx.x * 256 + threadIdx.x;
    float S = SzQz[0], Q = SzQz[1];
    float mu  = S * (1.f / 4096.f);
    float var = Q * (1.f / 4096.f) - mu * mu;
    float a   = gc2[0] * rsqrtf(var + EPSB);
    float cb  = bec2[0] - mu * a;
    float v = a * z[g] + cb;
    out[g] = 1.f / (1.f + expf(-v));
}

extern "C" void kernel_launch(void* const* d_in, const int* in_sizes, int n_in,
                              void* d_out, int out_size, void* d_ws, size_t ws_size,
                              hipStream_t stream)
{
    const float* x    = (const float*)d_in[0];
    const float* pos  = (const float*)d_in[1];
    // d_in[2] = batch (int32) — graphs are contiguous 64-node chunks; unused
    const float* W1   = (const float*)d_in[3];
    const float* b1   = (const float*)d_in[4];
    const float* g1   = (const float*)d_in[5];
    const float* be1  = (const float*)d_in[6];
    const float* W2   = (const float*)d_in[7];
    const float* b2   = (const float*)d_in[8];
    const float* g2   = (const float*)d_in[9];
    const float* be2  = (const float*)d_in[10];
    const float* Wc1  = (const float*)d_in[11];
    const float* bc1  = (const float*)d_in[12];
    const float* gc1  = (const float*)d_in[13];
    const float* bec1 = (const float*)d_in[14];
    const float* Wc2  = (const float*)d_in[15];
    const float* bc2  = (const float*)d_in[16];
    const float* gc2  = (const float*)d_in[17];
    const float* bec2 = (const float*)d_in[18];
    float* out = (float*)d_out;

    float* ws = (float*)d_ws;
    size_t off = 0;
    auto alloc = [&](size_t n) { float* p = ws + off; off += n; return p; };
    unsigned short* h1max = (unsigned short*)alloc((size_t)NN * H / 2);  // bf16, 67 MB
    unsigned short* W2t   = (unsigned short*)alloc(128 * 128 / 2);
    float* b2p     = alloc(H);
    float* graphsum= alloc((size_t)NB * H);
    float* c1raw   = alloc((size_t)NB * C1);
    float* zbuf    = alloc(NB);
    // atomic accumulators (contiguous; zeroed by one memset per iteration)
    const size_t ATOMN = (size_t)4 * NSH * H + 2 * C1 + 2;
    float* atomics = alloc(ATOMN);
    float* S1sh = atomics;
    float* Q1sh = S1sh + NSH * H;
    float* S2sh = Q1sh + NSH * H;
    float* Q2sh = S2sh + NSH * H;
    float* S3   = Q2sh + NSH * H;
    float* Q3   = S3 + C1;
    float* SzQz = Q3 + C1;

    hipMemsetAsync(atomics, 0, ATOMN * sizeof(float), stream);
    k_knn_mfma1<<<dim3(NB), dim3(512), 0, stream>>>(x, pos, W1, b1, h1max, S1sh, Q1sh);
    k_prep2<<<dim3(128), dim3(128), 0, stream>>>(W2, S1sh, Q1sh, g1, be1, b2, W2t, b2p);
    k_mfma2<<<dim3(NB), dim3(256), 0, stream>>>(h1max, W2t, b2p, graphsum, S2sh, Q2sh);
    k_cls1<<<dim3(256), dim3(256), 0, stream>>>(graphsum, S2sh, Q2sh, g2, be2, Wc1, bc1, c1raw, S3, Q3);
    k_cls2<<<dim3(256), dim3(256), 0, stream>>>(c1raw, S3, Q3, gc1, bec1, Wc2, bc2, zbuf, SzQz);
    k_final<<<dim3(16), dim3(256), 0, stream>>>(zbuf, SzQz, gc2, bec2, out);
}

// Round 7
// 234.350 us; speedup vs baseline: 1.1239x; 1.0855x over previous
//
#include <hip/hip_runtime.h>
#include <hip/hip_bf16.h>
#include <math.h>

// Problem constants
#define NB   4096      // graphs
#define MM   64        // points per graph
#define KNN  3
#define FX   59
#define H    128
#define NN   (NB*MM)       // 262144 nodes
#define NE   (NN*KNN)      // 786432 edges
#define C1   256
#define EPSB 1e-5f
#define NSH  16            // atomic shadow copies (contention = NB/NSH per addr)

typedef __attribute__((ext_vector_type(8))) short short8;   // 8 bf16 (4 VGPRs)
typedef __attribute__((ext_vector_type(4))) float f32x4;

__device__ __forceinline__ float wave_red(float v) {
#pragma unroll
    for (int m = 32; m >= 1; m >>= 1) v += __shfl_xor(v, m, 64);
    return v;
}

__device__ __forceinline__ void atomAddF(float* p, float v) {
    __hip_atomic_fetch_add(p, v, __ATOMIC_RELAXED, __HIP_MEMORY_SCOPE_AGENT);
}

__device__ __forceinline__ unsigned short f2bf(float f) {
    union { float f; unsigned u; } v; v.f = f;
    unsigned r = v.u + 0x7fffu + ((v.u >> 16) & 1u);   // round-to-nearest-even
    return (unsigned short)(r >> 16);
}

// pack two f32 -> u32 of 2 bf16 (lo = a, hi = b), RNE (v_cvt_pk_bf16_f32)
__device__ __forceinline__ unsigned int pack_bf2(float a, float b) {
    union { __hip_bfloat162 h; unsigned int u; } cv;
    cv.h = __float22bfloat162_rn(make_float2(a, b));
    return cv.u;
}

// ---------------------------------------------------------------------------
// K1, edge-matrix form: prepx -> a_s; kNN; build E (192x64: [x_j | p_j-p_i])
// in LDS; one MFMA pass E@W1 (swapped operands). A node's 3 edges sit at rows
// n, n+64, n+128 -> same lane, 3 accumulators -> relu+max+BN1 stats fully
// in-register (combine loop, u_s32 buffer, D-pack all deleted).
// 512 thr / 8 waves; LDS 38.9 KB -> 4 blocks/CU (32 waves).
// NOTE stride-72 (36 u32 = 4 mod 32) b128 reads are already bank-uniform
// (8 groups x 8 lanes = minimum); do NOT swizzle (r6: counter bit-identical).
// ---------------------------------------------------------------------------
__global__ __launch_bounds__(512, 8) void k_knn_mfma1(
    const float* __restrict__ x, const float* __restrict__ pos,
    const float* __restrict__ W1, const float* __restrict__ b1,
    unsigned short* __restrict__ h1max,
    float* __restrict__ S1sh, float* __restrict__ Q1sh)
{
    __shared__ float pos_s[MM * 3];
    __shared__ int   nbr_s[MM * 3];
    __shared__ float b1_s[H];
    __shared__ __align__(16) unsigned short a_s[MM * 72];       // [x|p|0,0] staging
    __shared__ __align__(16) unsigned short e_s[3 * MM * 72];   // edge features

    const int blk = blockIdx.x, tid = threadIdx.x;
    const float* xg = x + (size_t)blk * MM * FX;
    const float* pg = pos + (size_t)blk * MM * 3;

    // --- prepx: thread = one 16B granule of a node row
    {
        const int node = tid >> 3, c0g = (tid & 7) * 8;
        float v[8];
#pragma unroll
        for (int i = 0; i < 8; ++i) {
            int cI = c0g + i;
            v[i] = (cI < FX) ? xg[node * FX + cI]
                             : ((cI < 62) ? pg[node * 3 + (cI - FX)] : 0.f);
        }
        uint4 pk;
        pk.x = pack_bf2(v[0], v[1]); pk.y = pack_bf2(v[2], v[3]);
        pk.z = pack_bf2(v[4], v[5]); pk.w = pack_bf2(v[6], v[7]);
        *(uint4*)(a_s + node * 72 + c0g) = pk;
    }
    if (tid < MM * 3) pos_s[tid] = pg[tid];
    if (tid < H) b1_s[tid] = b1[tid];

    // --- W1 fragments straight from global (L2-hot)
    const int lane = tid & 63;
    const int w    = tid >> 6;          // 8 waves
    const int m    = lane & 15;
    const int kg   = lane >> 4;
    const int ch   = w * 16 + m;        // wave owns channels [w*16, w*16+16)

    short8 bfr[2];
#pragma unroll
    for (int kc = 0; kc < 2; ++kc) {
        float t8[8];
#pragma unroll
        for (int i = 0; i < 8; ++i) {
            int k = kc * 32 + kg * 8 + i;
            t8[i] = (k < 62) ? W1[k * H + ch] : 0.f;
        }
        uint4 pk;
        pk.x = pack_bf2(t8[0], t8[1]); pk.y = pack_bf2(t8[2], t8[3]);
        pk.z = pack_bf2(t8[4], t8[5]); pk.w = pack_bf2(t8[6], t8[7]);
        bfr[kc] = *(short8*)&pk;
    }
    __syncthreads();    // a_s, pos_s ready

    // --- parallel kNN: 8 threads per node, each scans 8 candidates; merge
    //     via shfl_xor(1,2,4). Lexicographic (d, idx) == top_k tie-break.
    {
        const int node = tid >> 3, q = tid & 7;
        const float px = pos_s[node * 3 + 0];
        const float py = pos_s[node * 3 + 1];
        const float pz = pos_s[node * 3 + 2];
        float d0 = 1e30f, d1 = 1e30f, d2 = 1e30f;
        int   i0 = 1 << 30, i1 = 1 << 30, i2 = 1 << 30;
        for (int jj = 0; jj < 8; ++jj) {
            int j = q * 8 + jj;
            if (j == node) continue;
            float dx = pos_s[j * 3 + 0] - px;
            float dy = pos_s[j * 3 + 1] - py;
            float dz = pos_s[j * 3 + 2] - pz;
            float d = dx * dx + dy * dy + dz * dz;
            bool b2v = (d < d2) || (d == d2 && j < i2);
            bool b1v = (d < d1) || (d == d1 && j < i1);
            bool b0v = (d < d0) || (d == d0 && j < i0);
            float nd2 = b1v ? d1 : d; int ni2 = b1v ? i1 : j;
            float nd1 = b0v ? d0 : d; int ni1 = b0v ? i0 : j;
            d2 = b2v ? nd2 : d2; i2 = b2v ? ni2 : i2;
            d1 = b1v ? nd1 : d1; i1 = b1v ? ni1 : i1;
            d0 = b0v ? d   : d0; i0 = b0v ? j   : i0;
        }
#pragma unroll
        for (int mq = 1; mq <= 4; mq <<= 1) {
            float e[3]; int f[3];
            e[0] = __shfl_xor(d0, mq, 64); f[0] = __shfl_xor(i0, mq, 64);
            e[1] = __shfl_xor(d1, mq, 64); f[1] = __shfl_xor(i1, mq, 64);
            e[2] = __shfl_xor(d2, mq, 64); f[2] = __shfl_xor(i2, mq, 64);
#pragma unroll
            for (int t3 = 0; t3 < 3; ++t3) {
                float ev = e[t3]; int fv = f[t3];
                bool b2v = (ev < d2) || (ev == d2 && fv < i2);
                bool b1v = (ev < d1) || (ev == d1 && fv < i1);
                bool b0v = (ev < d0) || (ev == d0 && fv < i0);
                float nd2 = b1v ? d1 : ev; int ni2 = b1v ? i1 : fv;
                float nd1 = b0v ? d0 : ev; int ni1 = b0v ? i0 : fv;
                d2 = b2v ? nd2 : d2; i2 = b2v ? ni2 : i2;
                d1 = b1v ? nd1 : d1; i1 = b1v ? ni1 : i1;
                d0 = b0v ? ev  : d0; i0 = b0v ? fv  : i0;
            }
        }
        if (q == 0) {
            nbr_s[node * 3 + 0] = i0;
            nbr_s[node * 3 + 1] = i1;
            nbr_s[node * 3 + 2] = i2;
        }
    }
    __syncthreads();    // nbr_s ready

    // --- E-build: row (slot*64+node) = a_s[j] with cols 59..61 patched to
    //     bf16(p_j - p_i), cols 62,63 = 0. 1536 granule tasks / 512 thr.
#pragma unroll
    for (int it = 0; it < 3; ++it) {
        const int T = tid + it * 512;
        const int row = T >> 3, g = T & 7;
        const int node = row & 63, slot = row >> 6;
        const int j = nbr_s[node * 3 + slot];
        if (g < 7) {
            *(uint4*)(e_s + row * 72 + g * 8) = *(const uint4*)(a_s + j * 72 + g * 8);
        } else {
            uint4 v = *(const uint4*)(a_s + j * 72 + 56);   // cols 56..63
            float r0 = pos_s[j * 3 + 0] - pos_s[node * 3 + 0];
            float r1 = pos_s[j * 3 + 1] - pos_s[node * 3 + 1];
            float r2 = pos_s[j * 3 + 2] - pos_s[node * 3 + 2];
            v.y = (v.y & 0xffffu) | ((unsigned)f2bf(r0) << 16);  // col59 (58 kept)
            v.z = pack_bf2(r1, r2);                              // cols 60,61
            v.w = 0u;                                            // cols 62,63
            *(uint4*)(e_s + row * 72 + 56) = v;
        }
    }
    __syncthreads();    // e_s ready

    // --- MFMA E@W1 per node-group; in-register relu/max/stats epilogue.
    // D layout: col(=E-row within tile) = lane&15, ch-sub = kg*4 + r.
    const int cb = w * 16 + kg * 4;          // 4 consecutive channels per lane
    const float b1v0 = b1_s[cb + 0], b1v1 = b1_s[cb + 1];
    const float b1v2 = b1_s[cb + 2], b1v3 = b1_s[cb + 3];
    float s0 = 0.f, s1 = 0.f, s2 = 0.f, s3 = 0.f;
    float q0 = 0.f, q1 = 0.f, q2 = 0.f, q3 = 0.f;
    unsigned int* hout32 = (unsigned int*)(h1max + (size_t)blk * MM * H);
#pragma unroll
    for (int rt4 = 0; rt4 < 4; ++rt4) {
        const int node = rt4 * 16 + m;
        f32x4 acc0 = (f32x4){0.f,0.f,0.f,0.f};
        f32x4 acc1 = (f32x4){0.f,0.f,0.f,0.f};
        f32x4 acc2 = (f32x4){0.f,0.f,0.f,0.f};
#pragma unroll
        for (int kc = 0; kc < 2; ++kc) {
            const int ko = kc * 32 + kg * 8;
            short8 a0 = *(const short8*)(e_s + (node      ) * 72 + ko);
            short8 a1 = *(const short8*)(e_s + (node +  64) * 72 + ko);
            short8 a2 = *(const short8*)(e_s + (node + 128) * 72 + ko);
            acc0 = __builtin_amdgcn_mfma_f32_16x16x32_bf16(bfr[kc], a0, acc0, 0, 0, 0);
            acc1 = __builtin_amdgcn_mfma_f32_16x16x32_bf16(bfr[kc], a1, acc1, 0, 0, 0);
            acc2 = __builtin_amdgcn_mfma_f32_16x16x32_bf16(bfr[kc], a2, acc2, 0, 0, 0);
        }
        float hm0, hm1, hm2, hm3;
        {
            float ha = fmaxf(acc0[0] + b1v0, 0.f), hb = fmaxf(acc1[0] + b1v0, 0.f), hc = fmaxf(acc2[0] + b1v0, 0.f);
            s0 += ha + hb + hc; q0 += ha * ha + hb * hb + hc * hc; hm0 = fmaxf(fmaxf(ha, hb), hc);
        }
        {
            float ha = fmaxf(acc0[1] + b1v1, 0.f), hb = fmaxf(acc1[1] + b1v1, 0.f), hc = fmaxf(acc2[1] + b1v1, 0.f);
            s1 += ha + hb + hc; q1 += ha * ha + hb * hb + hc * hc; hm1 = fmaxf(fmaxf(ha, hb), hc);
        }
        {
            float ha = fmaxf(acc0[2] + b1v2, 0.f), hb = fmaxf(acc1[2] + b1v2, 0.f), hc = fmaxf(acc2[2] + b1v2, 0.f);
            s2 += ha + hb + hc; q2 += ha * ha + hb * hb + hc * hc; hm2 = fmaxf(fmaxf(ha, hb), hc);
        }
        {
            float ha = fmaxf(acc0[3] + b1v3, 0.f), hb = fmaxf(acc1[3] + b1v3, 0.f), hc = fmaxf(acc2[3] + b1v3, 0.f);
            s3 += ha + hb + hc; q3 += ha * ha + hb * hb + hc * hc; hm3 = fmaxf(fmaxf(ha, hb), hc);
        }
        uint2 val;
        val.x = pack_bf2(hm0, hm1);
        val.y = pack_bf2(hm2, hm3);
        *(uint2*)(hout32 + node * 64 + w * 8 + kg * 2) = val;
    }
    __syncthreads();    // all e_s reads done; reuse as reduction buffer

    // --- BN1 partial reduce: red[ch][m] (s), red[2048 + ch*16 + m] (q)
    float* red = (float*)e_s;   // 4096 floats = 16 KB <= 27.6 KB
    red[(cb + 0) * 16 + m] = s0;
    red[(cb + 1) * 16 + m] = s1;
    red[(cb + 2) * 16 + m] = s2;
    red[(cb + 3) * 16 + m] = s3;
    red[2048 + (cb + 0) * 16 + m] = q0;
    red[2048 + (cb + 1) * 16 + m] = q1;
    red[2048 + (cb + 2) * 16 + m] = q2;
    red[2048 + (cb + 3) * 16 + m] = q3;
    __syncthreads();
    const int sel = blk & (NSH - 1);
    if (tid < H) {
        float S = 0.f;
#pragma unroll
        for (int mm = 0; mm < 16; ++mm) S += red[tid * 16 + mm];
        atomAddF(&S1sh[sel * H + tid], S);
    } else if (tid < 2 * H) {
        const int t2 = tid - H;
        float Q = 0.f;
#pragma unroll
        for (int mm = 0; mm < 16; ++mm) Q += red[2048 + t2 * 16 + mm];
        atomAddF(&Q1sh[sel * H + t2], Q);
    }
}

// ---------------------------------------------------------------------------
// prep2: fold 16 BN1 shadows -> affine1 in-register; emit W2t (affine folded)
// and b2p. grid=128, blk=128.
// ---------------------------------------------------------------------------
__global__ __launch_bounds__(128) void k_prep2(
    const float* __restrict__ W2, const float* __restrict__ S1sh,
    const float* __restrict__ Q1sh, const float* __restrict__ g1,
    const float* __restrict__ be1, const float* __restrict__ b2,
    unsigned short* __restrict__ W2t, float* __restrict__ b2p)
{
    const int n = blockIdx.x, k = threadIdx.x;
    float S = 0.f, Q = 0.f;
#pragma unroll
    for (int i = 0; i < NSH; ++i) { S += S1sh[i * H + k]; Q += Q1sh[i * H + k]; }
    float mu  = S * (1.f / (float)NE);
    float var = Q * (1.f / (float)NE) - mu * mu;
    float a   = g1[k] * rsqrtf(var + EPSB);
    float cc  = be1[k] - mu * a;
    float wv  = W2[k * H + n];
    W2t[n * H + k] = f2bf(a * wv);
    float contrib = wave_red(cc * wv);
    __shared__ float red2[2];
    if ((k & 63) == 0) red2[k >> 6] = contrib;
    __syncthreads();
    if (k == 0) b2p[n] = b2[n] + red2[0] + red2[1];
}

// ---------------------------------------------------------------------------
// K3: h2 = relu(h1max(bf16) @ W2t + b2p) via MFMA; graphsum + shadowed
// atomic BN2 stats. LDS-staged. grid=4096, 256 thr.
// ---------------------------------------------------------------------------
__global__ __launch_bounds__(256) void k_mfma2(
    const unsigned short* __restrict__ h1max, const unsigned short* __restrict__ W2t,
    const float* __restrict__ b2p,
    float* __restrict__ graphsum, float* __restrict__ S2sh, float* __restrict__ Q2sh)
{
    __shared__ __align__(16) unsigned short a_s[MM * 136];  // 64x128 bf16, stride 136
    const int blk = blockIdx.x, tid = threadIdx.x;
    const unsigned short* hg = h1max + (size_t)blk * MM * H;
    for (int t = tid; t < MM * H / 8; t += 256) {
        int row = t >> 4, col8 = (t & 15) * 8;
        *(short8*)(a_s + row * 136 + col8) = *(const short8*)(hg + row * H + col8);
    }
    __syncthreads();

    const int lane = tid & 63, w = tid >> 6, wcol = w * 32;
    const int m = lane & 15, kg = lane >> 4;

    short8 bfr[2][4];
#pragma unroll
    for (int ct = 0; ct < 2; ++ct)
#pragma unroll
        for (int kc = 0; kc < 4; ++kc)
            bfr[ct][kc] = *(const short8*)(W2t + (wcol + ct * 16 + m) * H + kc * 32 + kg * 8);

    f32x4 acc[4][2];
#pragma unroll
    for (int rt = 0; rt < 4; ++rt)
#pragma unroll
        for (int ct = 0; ct < 2; ++ct) acc[rt][ct] = (f32x4){0.f, 0.f, 0.f, 0.f};

#pragma unroll
    for (int kc = 0; kc < 4; ++kc)
#pragma unroll
        for (int rt = 0; rt < 4; ++rt) {
            short8 a = *(const short8*)(a_s + (rt * 16 + m) * 136 + kc * 32 + kg * 8);
#pragma unroll
            for (int ct = 0; ct < 2; ++ct)
                acc[rt][ct] = __builtin_amdgcn_mfma_f32_16x16x32_bf16(a, bfr[ct][kc], acc[rt][ct], 0, 0, 0);
        }

    const int sel = blk & (NSH - 1);
#pragma unroll
    for (int ct = 0; ct < 2; ++ct) {
        float bv = b2p[wcol + ct * 16 + m];
        float s = 0.f, q = 0.f;
#pragma unroll
        for (int rt = 0; rt < 4; ++rt)
#pragma unroll
            for (int r = 0; r < 4; ++r) {
                float v = fmaxf(acc[rt][ct][r] + bv, 0.f);
                s += v; q += v * v;
            }
        s += __shfl_xor(s, 16, 64); q += __shfl_xor(q, 16, 64);
        s += __shfl_xor(s, 32, 64); q += __shfl_xor(q, 32, 64);
        if (lane < 16) {
            int col = wcol + ct * 16 + lane;
            graphsum[(size_t)blk * H + col] = s;
            atomAddF(&S2sh[sel * H + col], s);
            atomAddF(&Q2sh[sel * H + col], q);
        }
    }
}

// ---------------------------------------------------------------------------
// cls1: affine2 inline from shadows; pooled = BN2(graphsum/64);
// c1 = ReLU(pooled @ Wc1 + bc1); BN3 stats via direct atomics.
// grid=256, blk=256 (16 graphs per block).
// ---------------------------------------------------------------------------
__global__ __launch_bounds__(256) void k_cls1(
    const float* __restrict__ graphsum,
    const float* __restrict__ S2sh, const float* __restrict__ Q2sh,
    const float* __restrict__ g2, const float* __restrict__ be2,
    const float* __restrict__ Wc1, const float* __restrict__ bc1,
    float* __restrict__ c1raw, float* __restrict__ S3, float* __restrict__ Q3)
{
    __shared__ float a2_s[H], c2_s[H];
    const int blk = blockIdx.x, tid = threadIdx.x;
    if (tid < H) {
        float S = 0.f, Q = 0.f;
#pragma unroll
        for (int i = 0; i < NSH; ++i) { S += S2sh[i * H + tid]; Q += Q2sh[i * H + tid]; }
        float mu  = S * (1.f / (float)NN);
        float var = Q * (1.f / (float)NN) - mu * mu;
        float a   = g2[tid] * rsqrtf(var + EPSB);
        a2_s[tid] = a;
        c2_s[tid] = be2[tid] - mu * a;
    }
    __syncthreads();
    __shared__ float pooled_s[16 * H];
    const int g0 = blk * 16;
    for (int t = tid; t < 16 * H; t += 256) {
        int f = t & 127;
        pooled_s[t] = a2_s[f] * (graphsum[(size_t)g0 * H + t] * (1.f / 64.f)) + c2_s[f];
    }
    __syncthreads();
    const int c = tid;
    float acc[16];
    const float bias = bc1[c];
#pragma unroll
    for (int gi = 0; gi < 16; ++gi) acc[gi] = bias;
    for (int f = 0; f < H; ++f) {
        float wv = Wc1[f * C1 + c];
#pragma unroll
        for (int gi = 0; gi < 16; ++gi) acc[gi] += pooled_s[gi * H + f] * wv;
    }
    float s = 0.f, q = 0.f;
#pragma unroll
    for (int gi = 0; gi < 16; ++gi) {
        float h = fmaxf(acc[gi], 0.f);
        c1raw[(size_t)(g0 + gi) * C1 + c] = h;
        s += h; q += h * h;
    }
    atomAddF(&S3[c], s);
    atomAddF(&Q3[c], q);
}

// ---------------------------------------------------------------------------
// cls2: affine3 inline from S3/Q3; z = ReLU(BN3(c1) @ Wc2 + bc2);
// final-BN scalar stats via atomics. grid=256, blk=256 (16 lanes/graph).
// ---------------------------------------------------------------------------
__global__ __launch_bounds__(256) void k_cls2(
    const float* __restrict__ c1raw,
    const float* __restrict__ S3, const float* __restrict__ Q3,
    const float* __restrict__ gc1, const float* __restrict__ bec1,
    const float* __restrict__ Wc2, const float* __restrict__ bc2,
    float* __restrict__ z, float* __restrict__ SzQz)
{
    __shared__ float a3_s[C1], c3_s[C1], w3_s[C1];
    __shared__ float zloc[16];
    const int blk = blockIdx.x, tid = threadIdx.x;
    {
        float S = S3[tid], Q = Q3[tid];
        float mu  = S * (1.f / (float)NB);
        float var = Q * (1.f / (float)NB) - mu * mu;
        float a   = gc1[tid] * rsqrtf(var + EPSB);
        a3_s[tid] = a;
        c3_s[tid] = bec1[tid] - mu * a;
        w3_s[tid] = Wc2[tid];
    }
    __syncthreads();
    const int g0 = blk * 16;
    {
        const int gi = tid >> 4, part = tid & 15;
        const float* crow = c1raw + (size_t)(g0 + gi) * C1 + part * 16;
        float acc3 = 0.f;
#pragma unroll
        for (int i = 0; i < 16; i += 4) {
            float4 cv = *(const float4*)(crow + i);
            int f = part * 16 + i;
            acc3 += (a3_s[f + 0] * cv.x + c3_s[f + 0]) * w3_s[f + 0];
            acc3 += (a3_s[f + 1] * cv.y + c3_s[f + 1]) * w3_s[f + 1];
            acc3 += (a3_s[f + 2] * cv.z + c3_s[f + 2]) * w3_s[f + 2];
            acc3 += (a3_s[f + 3] * cv.w + c3_s[f + 3]) * w3_s[f + 3];
        }
#pragma unroll
        for (int mm = 1; mm <= 8; mm <<= 1) acc3 += __shfl_xor(acc3, mm, 64);
        if (part == 0) zloc[gi] = fmaxf(acc3 + bc2[0], 0.f);
    }
    __syncthreads();
    if (tid < 16) z[g0 + tid] = zloc[tid];
    if (tid == 0) {
        float s = 0.f, q = 0.f;
#pragma unroll
        for (int i = 0; i < 16; ++i) { float zz = zloc[i]; s += zz; q += zz * zz; }
        atomAddF(&SzQz[0], s);
        atomAddF(&SzQz[1], q);
    }
}

// ---------------------------------------------------------------------------
// final: BN over 4096 z (stats from SzQz) + sigmoid. grid=16, blk=256.
// ---------------------------------------------------------------------------
__global__ __launch_bounds__(256) void k_final(
    const float* __restrict__ z, const float* __restrict__ SzQz,
    const float* __restrict__ gc2, const float* __restrict__ bec2,
    float* __restrict__ out)
{
    const int g = blockIdx.x * 256 + threadIdx.x;
    float S = SzQz[0], Q = SzQz[1];
    float mu  = S * (1.f / 4096.f);
    float var = Q * (1.f / 4096.f) - mu * mu;
    float a   = gc2[0] * rsqrtf(var + EPSB);
    float cb  = bec2[0] - mu * a;
    float v = a * z[g] + cb;
    out[g] = 1.f / (1.f + expf(-v));
}

extern "C" void kernel_launch(void* const* d_in, const int* in_sizes, int n_in,
                              void* d_out, int out_size, void* d_ws, size_t ws_size,
                              hipStream_t stream)
{
    const float* x    = (const float*)d_in[0];
    const float* pos  = (const float*)d_in[1];
    // d_in[2] = batch (int32) — graphs are contiguous 64-node chunks; unused
    const float* W1   = (const float*)d_in[3];
    const float* b1   = (const float*)d_in[4];
    const float* g1   = (const float*)d_in[5];
    const float* be1  = (const float*)d_in[6];
    const float* W2   = (const float*)d_in[7];
    const float* b2   = (const float*)d_in[8];
    const float* g2   = (const float*)d_in[9];
    const float* be2  = (const float*)d_in[10];
    const float* Wc1  = (const float*)d_in[11];
    const float* bc1  = (const float*)d_in[12];
    const float* gc1  = (const float*)d_in[13];
    const float* bec1 = (const float*)d_in[14];
    const float* Wc2  = (const float*)d_in[15];
    const float* bc2  = (const float*)d_in[16];
    const float* gc2  = (const float*)d_in[17];
    const float* bec2 = (const float*)d_in[18];
    float* out = (float*)d_out;

    float* ws = (float*)d_ws;
    size_t off = 0;
    auto alloc = [&](size_t n) { float* p = ws + off; off += n; return p; };
    unsigned short* h1max = (unsigned short*)alloc((size_t)NN * H / 2);  // bf16, 67 MB
    unsigned short* W2t   = (unsigned short*)alloc(128 * 128 / 2);
    float* b2p     = alloc(H);
    float* graphsum= alloc((size_t)NB * H);
    float* c1raw   = alloc((size_t)NB * C1);
    float* zbuf    = alloc(NB);
    // atomic accumulators (contiguous; zeroed by one memset per iteration)
    const size_t ATOMN = (size_t)4 * NSH * H + 2 * C1 + 2;
    float* atomics = alloc(ATOMN);
    float* S1sh = atomics;
    float* Q1sh = S1sh + NSH * H;
    float* S2sh = Q1sh + NSH * H;
    float* Q2sh = S2sh + NSH * H;
    float* S3   = Q2sh + NSH * H;
    float* Q3   = S3 + C1;
    float* SzQz = Q3 + C1;

    hipMemsetAsync(atomics, 0, ATOMN * sizeof(float), stream);
    k_knn_mfma1<<<dim3(NB), dim3(512), 0, stream>>>(x, pos, W1, b1, h1max, S1sh, Q1sh);
    k_prep2<<<dim3(128), dim3(128), 0, stream>>>(W2, S1sh, Q1sh, g1, be1, b2, W2t, b2p);
    k_mfma2<<<dim3(NB), dim3(256), 0, stream>>>(h1max, W2t, b2p, graphsum, S2sh, Q2sh);
    k_cls1<<<dim3(256), dim3(256), 0, stream>>>(graphsum, S2sh, Q2sh, g2, be2, Wc1, bc1, c1raw, S3, Q3);
    k_cls2<<<dim3(256), dim3(256), 0, stream>>>(c1raw, S3, Q3, gc1, bec1, Wc2, bc2, zbuf, SzQz);
    k_final<<<dim3(16), dim3(256), 0, stream>>>(zbuf, SzQz, gc2, bec2, out);
}